// Round 1
// baseline (219.055 us; speedup 1.0000x reference)
//
#include <hip/hip_runtime.h>
#include <math.h>

#define H 512
#define W 512
#define HW (H * W)
#define NCH 6

__device__ __forceinline__ int reflect_idx(int p, int n) {
    if (p < 0) p = -p;
    if (p >= n) p = 2 * n - 2 - p;
    return p;
}

// ---------------- K0: zero the atomic-max slots ----------------
__global__ void k_init(unsigned int* maxbits) {
    if (threadIdx.x < 12) maxbits[threadIdx.x] = 0u;
}

// ---------------- K1: per-channel max of img ----------------
__global__ __launch_bounds__(256) void k_imgmax(const float* __restrict__ img,
                                                unsigned int* __restrict__ maxbits) {
    int ch = blockIdx.y;
    int t = threadIdx.x;
    const float4* p4 = (const float4*)(img + (size_t)ch * HW + (size_t)blockIdx.x * 4096);
    float m = 0.f;
#pragma unroll
    for (int k = 0; k < 4; ++k) {
        float4 v = p4[k * 256 + t];
        m = fmaxf(m, fmaxf(fmaxf(v.x, v.y), fmaxf(v.z, v.w)));
    }
    __shared__ float red[256];
    red[t] = m;
    __syncthreads();
    for (int s = 128; s > 0; s >>= 1) {
        if (t < s) red[t] = fmaxf(red[t], red[t + s]);
        __syncthreads();
    }
    if (t == 0) atomicMax(&maxbits[ch], __float_as_uint(red[0]));
}

// ---------------- K2: Sobel -> g, xn, yn (rotated), gmag max ----------------
__global__ __launch_bounds__(256) void k_sobel(const float* __restrict__ img,
                                               const unsigned int* __restrict__ imgmaxbits,
                                               unsigned int* __restrict__ gmaxbits,
                                               float* __restrict__ g,
                                               float* __restrict__ xn,
                                               float* __restrict__ yn) {
    int ch = blockIdx.z;
    int x = blockIdx.x * 32 + threadIdx.x;
    int y = blockIdx.y * 8 + threadIdx.y;
    const float* im = img + (size_t)ch * HW;
    float cmax = __uint_as_float(imgmaxbits[ch]);

    auto At = [&](int yy, int xx) -> float {
        if (yy < 0 || yy >= H || xx < 0 || xx >= W) return 0.f;
        return im[yy * W + xx] / cmax;   // per-element division, matches ref rounding
    };
    float a00 = At(y - 1, x - 1), a01 = At(y - 1, x), a02 = At(y - 1, x + 1);
    float a10 = At(y, x - 1), a12 = At(y, x + 1);
    float a20 = At(y + 1, x - 1), a21 = At(y + 1, x), a22 = At(y + 1, x + 1);

    // cross-correlation, row-major tap order
    float gx = -a00; gx += a02; gx -= 2.f * a10; gx += 2.f * a12; gx -= a20; gx += a22;
    float gy = -a00; gy -= 2.f * a01; gy -= a02; gy += a20; gy += 2.f * a21; gy += a22;

    gx = fmaxf(gx, 1e-12f);
    gy = fmaxf(gy, 1e-12f);
    float gm = sqrtf(gx * gx + gy * gy);
    float xv = gx / gm, yv = gy / gm;

    // rotate by fp32(pi/2): ct = cos, st = 1.0 exactly
    const float ct = -4.37113883e-08f;
    float xr = xv * ct - yv;
    float yr = yv * ct + xv;

    size_t idx = (size_t)ch * HW + (size_t)y * W + x;
    g[idx] = gm;
    xn[idx] = xr;
    yn[idx] = yr;

    // block-reduce max of gm -> atomic
    __shared__ float red[256];
    int tid = threadIdx.y * 32 + threadIdx.x;
    red[tid] = gm;
    __syncthreads();
    for (int s = 128; s > 0; s >>= 1) {
        if (tid < s) red[tid] = fmaxf(red[tid], red[tid + s]);
        __syncthreads();
    }
    if (tid == 0) atomicMax(&gmaxbits[ch], __float_as_uint(red[0]));
}

// ---------------- K3: one ETF iteration (templated: LAST fuses angle+partials) --------
template <bool LAST>
__global__ __launch_bounds__(256) void k_iter(const float* __restrict__ g,
                                              const float* __restrict__ xin,
                                              const float* __restrict__ yin,
                                              const unsigned int* __restrict__ gmaxbits,
                                              float* __restrict__ xout,
                                              float* __restrict__ yout,
                                              double* __restrict__ partials) {
    const int TW = 32, TH = 8, SW = 36, SH = 12;
    __shared__ float sg[SH * SW], sx[SH * SW], sy[SH * SW];

    int ch = blockIdx.z;
    int bx0 = blockIdx.x * TW - 2, by0 = blockIdx.y * TH - 2;
    int tid = threadIdx.y * TW + threadIdx.x;
    const size_t cbase = (size_t)ch * HW;

    for (int i = tid; i < SH * SW; i += 256) {
        int r = i / SW, c = i - r * SW;
        int yy = reflect_idx(by0 + r, H);
        int xx = reflect_idx(bx0 + c, W);
        size_t idx = cbase + (size_t)yy * W + xx;
        sg[i] = g[idx];
        sx[i] = xin[idx];
        sy[i] = yin[idx];
    }
    __syncthreads();

    float inv = 1.f / __uint_as_float(gmaxbits[ch]);
    float s2 = -2.f * inv;  // sigmoid(2*inv*d) = 0.5*(1+tanh(inv*d))

    int cidx = (threadIdx.y + 2) * SW + (threadIdx.x + 2);
    float cg = sg[cidx], cx = sx[cidx], cy = sy[cidx];
    float xr = 0.f, yr = 0.f;
#pragma unroll
    for (int dy = -2; dy <= 2; ++dy) {
#pragma unroll
        for (int dx = -2; dx <= 2; ++dx) {
            int n = cidx + dy * SW + dx;
            float ng = sg[n], nx = sx[n], ny = sy[n];
            float dot = cx * nx + cy * ny;
            float e = __expf(s2 * (ng - cg));
            float wm = __builtin_amdgcn_rcpf(1.f + e);
            float m = ng * (wm * dot);
            xr = fmaf(m, nx, xr);
            yr = fmaf(m, ny, yr);
        }
    }
    float mag = sqrtf(xr * xr + yr * yr);
    float xnn = xr / mag, ynn = yr / mag;

    int x = blockIdx.x * TW + threadIdx.x, y = blockIdx.y * TH + threadIdx.y;
    size_t oidx = cbase + (size_t)y * W + x;

    if (!LAST) {
        xout[oidx] = xnn;
        yout[oidx] = ynn;
    } else {
        float ang = atanf(-ynn / xnn);
        float a = (180.f * ang) / 3.14159274f;  // fp32 pi, ref op order
        xout[oidx] = a;

        __shared__ double rs[256], rq[256];
        rs[tid] = (double)a;
        rq[tid] = (double)a * (double)a;
        __syncthreads();
        for (int s = 128; s > 0; s >>= 1) {
            if (tid < s) {
                rs[tid] += rs[tid + s];
                rq[tid] += rq[tid + s];
            }
            __syncthreads();
        }
        if (tid == 0) {
            int blk = blockIdx.y * 16 + blockIdx.x;  // 1024 blocks per channel
            partials[((size_t)ch * 1024 + blk) * 2 + 0] = rs[0];
            partials[((size_t)ch * 1024 + blk) * 2 + 1] = rq[0];
        }
    }
}

// ---------------- K5: reduce partials -> mean, invstd per channel ----------------
__global__ __launch_bounds__(256) void k_stats(const double* __restrict__ partials,
                                               float* __restrict__ stats) {
    int ch = blockIdx.x;
    int t = threadIdx.x;
    double s = 0.0, q = 0.0;
#pragma unroll
    for (int k = 0; k < 4; ++k) {
        size_t i = (size_t)ch * 1024 + t * 4 + k;
        s += partials[i * 2 + 0];
        q += partials[i * 2 + 1];
    }
    __shared__ double rs[256], rq[256];
    rs[t] = s;
    rq[t] = q;
    __syncthreads();
    for (int st = 128; st > 0; st >>= 1) {
        if (t < st) {
            rs[t] += rs[t + st];
            rq[t] += rq[t + st];
        }
        __syncthreads();
    }
    if (t == 0) {
        double mean = rs[0] / (double)HW;
        double var = rq[0] / (double)HW - mean * mean;
        stats[ch] = (float)mean;
        stats[6 + ch] = (float)(1.0 / sqrt(var + 1e-5));
    }
}

// ---------------- K6: in-place instance norm on d_out ----------------
__global__ __launch_bounds__(256) void k_norm(float* __restrict__ a,
                                              const float* __restrict__ stats) {
    int ch = blockIdx.y;
    float mean = stats[ch], sc = stats[6 + ch];
    float4* a4 = (float4*)(a + (size_t)ch * HW);
    int i = blockIdx.x * 256 + threadIdx.x;
    float4 v = a4[i];
    v.x = (v.x - mean) * sc;
    v.y = (v.y - mean) * sc;
    v.z = (v.z - mean) * sc;
    v.w = (v.w - mean) * sc;
    a4[i] = v;
}

extern "C" void kernel_launch(void* const* d_in, const int* in_sizes, int n_in,
                              void* d_out, int out_size, void* d_ws, size_t ws_size,
                              hipStream_t stream) {
    (void)in_sizes; (void)n_in; (void)out_size; (void)ws_size;
    const float* img = (const float*)d_in[0];
    float* out = (float*)d_out;

    float* wsf = (float*)d_ws;
    unsigned int* maxbits = (unsigned int*)d_ws;    // [0..5] img max bits, [6..11] gmag max bits
    float* stats = wsf + 16;                        // mean[6], invstd[6]
    double* partials = (double*)(wsf + 32);         // 6*1024*2 doubles = 96 KiB
    float* g = wsf + 32768;                         // 128 KiB offset, then 5 fields of 6 MiB
    float* xnA = g + (size_t)NCH * HW;
    float* ynA = xnA + (size_t)NCH * HW;
    float* xnB = ynA + (size_t)NCH * HW;
    float* ynB = xnB + (size_t)NCH * HW;

    dim3 tile_grid(16, 64, NCH), tile_blk(32, 8);

    k_init<<<dim3(1), dim3(16), 0, stream>>>(maxbits);
    k_imgmax<<<dim3(64, NCH), dim3(256), 0, stream>>>(img, maxbits);
    k_sobel<<<tile_grid, tile_blk, 0, stream>>>(img, maxbits, maxbits + 6, g, xnA, ynA);
    k_iter<false><<<tile_grid, tile_blk, 0, stream>>>(g, xnA, ynA, maxbits + 6, xnB, ynB, nullptr);
    k_iter<false><<<tile_grid, tile_blk, 0, stream>>>(g, xnB, ynB, maxbits + 6, xnA, ynA, nullptr);
    k_iter<true><<<tile_grid, tile_blk, 0, stream>>>(g, xnA, ynA, maxbits + 6, out, nullptr, partials);
    k_stats<<<dim3(NCH), dim3(256), 0, stream>>>(partials, stats);
    k_norm<<<dim3(256, NCH), dim3(256), 0, stream>>>(out, stats);
}

// Round 2
// 203.149 us; speedup vs baseline: 1.0783x; 1.0783x over previous
//
#include <hip/hip_runtime.h>
#include <math.h>

#define H 512
#define W 512
#define HW (H * W)
#define NCH 6

__device__ __forceinline__ int reflect_idx(int p, int n) {
    if (p < 0) p = -p;
    if (p >= n) p = 2 * n - 2 - p;
    return p;
}

// ---------------- K0: zero the atomic-max slots ----------------
__global__ void k_init(unsigned int* maxbits) {
    if (threadIdx.x < 12) maxbits[threadIdx.x] = 0u;
}

// ---------------- K1: per-channel max of img ----------------
__global__ __launch_bounds__(256) void k_imgmax(const float* __restrict__ img,
                                                unsigned int* __restrict__ maxbits) {
    int ch = blockIdx.y;
    int t = threadIdx.x;
    const float4* p4 = (const float4*)(img + (size_t)ch * HW + (size_t)blockIdx.x * 4096);
    float m = 0.f;
#pragma unroll
    for (int k = 0; k < 4; ++k) {
        float4 v = p4[k * 256 + t];
        m = fmaxf(m, fmaxf(fmaxf(v.x, v.y), fmaxf(v.z, v.w)));
    }
    __shared__ float red[256];
    red[t] = m;
    __syncthreads();
    for (int s = 128; s > 0; s >>= 1) {
        if (t < s) red[t] = fmaxf(red[t], red[t + s]);
        __syncthreads();
    }
    if (t == 0) atomicMax(&maxbits[ch], __float_as_uint(red[0]));
}

// ---------------- K2: Sobel (LDS-tiled) -> g, xn, yn (rotated), gmag max ----------------
// Scale-invariance: Sobel on RAW img, then one multiply by 1/cmax before the 1e-12 clamp.
__global__ __launch_bounds__(256) void k_sobel(const float* __restrict__ img,
                                               const unsigned int* __restrict__ imgmaxbits,
                                               unsigned int* __restrict__ gmaxbits,
                                               float* __restrict__ g,
                                               float* __restrict__ xn,
                                               float* __restrict__ yn) {
    const int SW = 36, SH = 10;  // 32x8 tile + halo 1, padded row
    __shared__ float st[SH * SW];

    int ch = blockIdx.z;
    int bx0 = blockIdx.x * 32, by0 = blockIdx.y * 8;
    int tx = threadIdx.x, ty = threadIdx.y;
    int tid = ty * 32 + tx;
    const float* im = img + (size_t)ch * HW;

#pragma unroll
    for (int it = 0; it < 2; ++it) {
        int i = tid + it * 256;
        if (i < SH * 34) {
            int r = i / 34, c = i - r * 34;
            int yy = by0 - 1 + r, xx = bx0 - 1 + c;
            float v = 0.f;
            if (yy >= 0 && yy < H && xx >= 0 && xx < W) v = im[yy * W + xx];  // zero pad
            st[r * SW + c] = v;
        }
    }
    __syncthreads();

    float invc = 1.f / __uint_as_float(imgmaxbits[ch]);

    int r = ty + 1, c = tx + 1;
    float a00 = st[(r - 1) * SW + c - 1], a01 = st[(r - 1) * SW + c], a02 = st[(r - 1) * SW + c + 1];
    float a10 = st[r * SW + c - 1], a12 = st[r * SW + c + 1];
    float a20 = st[(r + 1) * SW + c - 1], a21 = st[(r + 1) * SW + c], a22 = st[(r + 1) * SW + c + 1];

    float gx = -a00; gx += a02; gx -= 2.f * a10; gx += 2.f * a12; gx -= a20; gx += a22;
    float gy = -a00; gy -= 2.f * a01; gy -= a02; gy += a20; gy += 2.f * a21; gy += a22;

    gx = fmaxf(gx * invc, 1e-12f);
    gy = fmaxf(gy * invc, 1e-12f);
    float d = gx * gx + gy * gy;
    float rq = __builtin_amdgcn_rsqf(d);
    float gm = d * rq;                 // = sqrt(d), ~1e-7 rel err
    float xv = gx * rq, yv = gy * rq;

    // rotate by fp32(pi/2): ct = cosf, st = 1.0 exactly
    const float ct = -4.37113883e-08f;
    float xr = xv * ct - yv;
    float yr = yv * ct + xv;

    size_t idx = (size_t)ch * HW + (size_t)(by0 + ty) * W + (bx0 + tx);
    g[idx] = gm;
    xn[idx] = xr;
    yn[idx] = yr;

    __syncthreads();  // reuse st for the max reduction
    st[tid] = gm;
    __syncthreads();
    for (int s = 128; s > 0; s >>= 1) {
        if (tid < s) st[tid] = fmaxf(st[tid], st[tid + s]);
        __syncthreads();
    }
    if (tid == 0) atomicMax(&gmaxbits[ch], __float_as_uint(st[0]));
}

// ---------------- K3: one ETF iteration, 4 px/thread (LAST fuses angle+partials) -------
template <bool LAST>
__global__ __launch_bounds__(256) void k_iter(const float* __restrict__ g,
                                              const float* __restrict__ xin,
                                              const float* __restrict__ yin,
                                              const unsigned int* __restrict__ gmaxbits,
                                              float* __restrict__ xout,
                                              float* __restrict__ yout,
                                              double* __restrict__ partials) {
    const int SW = 136, SH = 12;  // tile 128x8 + halo 2; row padded to 136 (16B-aligned quads)
    __shared__ __align__(16) float sg[SH * SW];
    __shared__ __align__(16) float sx[SH * SW];
    __shared__ __align__(16) float sy[SH * SW];

    int ch = blockIdx.z;
    int bx0 = blockIdx.x * 128, by0 = blockIdx.y * 8;
    int tx = threadIdx.x, ty = threadIdx.y;
    int tid = ty * 32 + tx;
    const size_t cbase = (size_t)ch * HW;

    // stage rows r: image y = by0-2+r ; cols c (0..131): image x = bx0-2+c (reflect)
    for (int i = tid; i < SH * 132; i += 256) {
        int r = i / 132, c = i - r * 132;
        int yy = reflect_idx(by0 - 2 + r, H);
        int xx = reflect_idx(bx0 - 2 + c, W);
        size_t idx = cbase + (size_t)yy * W + xx;
        int s = r * SW + c;
        sg[s] = g[idx];
        sx[s] = xin[idx];
        sy[s] = yin[idx];
    }
    __syncthreads();

    float inv = 1.f / __uint_as_float(gmaxbits[ch]);
    float s2 = -2.f * inv;  // sigmoid(2*inv*d) = 0.5*(1+tanh(inv*d))

    // thread handles pixels x = bx0 + 4*tx + k, k=0..3; LDS center col = 4*tx+2+k
    auto ld8 = [&](const float* s, int r, float* w) {
        const float4* p = (const float4*)(s + r * SW + 4 * tx);
        float4 a = p[0], b = p[1];
        w[0] = a.x; w[1] = a.y; w[2] = a.z; w[3] = a.w;
        w[4] = b.x; w[5] = b.y; w[6] = b.z; w[7] = b.w;
    };

    int row0 = ty + 2;
    float cgw[8], cxw[8], cyw[8];
    ld8(sg, row0, cgw);
    ld8(sx, row0, cxw);
    ld8(sy, row0, cyw);
    float cg[4], cx[4], cy[4], ec[4];
#pragma unroll
    for (int k = 0; k < 4; ++k) {
        cg[k] = cgw[k + 2];
        cx[k] = cxw[k + 2];
        cy[k] = cyw[k + 2];
        ec[k] = __expf(-s2 * cg[k]);  // e^{s2(ng-cg)} = e^{s2 ng} * ec
    }

    float xr[4] = {0.f, 0.f, 0.f, 0.f}, yr[4] = {0.f, 0.f, 0.f, 0.f};
#pragma unroll
    for (int dy = -2; dy <= 2; ++dy) {
        float gw[8], xw[8], yw[8], ew[8];
        ld8(sg, row0 + dy, gw);
        ld8(sx, row0 + dy, xw);
        ld8(sy, row0 + dy, yw);
#pragma unroll
        for (int n = 0; n < 8; ++n) ew[n] = __expf(s2 * gw[n]);
#pragma unroll
        for (int k = 0; k < 4; ++k) {
#pragma unroll
            for (int dxi = 0; dxi < 5; ++dxi) {
                int n = k + dxi;
                float dot = cx[k] * xw[n] + cy[k] * yw[n];
                float wm = __builtin_amdgcn_rcpf(1.f + ew[n] * ec[k]);
                float m = gw[n] * (wm * dot);
                xr[k] = fmaf(m, xw[n], xr[k]);
                yr[k] = fmaf(m, yw[n], yr[k]);
            }
        }
    }

    size_t obase = cbase + (size_t)(by0 + ty) * W + bx0 + 4 * tx;
    if (!LAST) {
        float ox[4], oy[4];
#pragma unroll
        for (int k = 0; k < 4; ++k) {
            float im2 = __builtin_amdgcn_rsqf(xr[k] * xr[k] + yr[k] * yr[k]);
            ox[k] = xr[k] * im2;
            oy[k] = yr[k] * im2;
        }
        *(float4*)(xout + obase) = make_float4(ox[0], ox[1], ox[2], ox[3]);
        *(float4*)(yout + obase) = make_float4(oy[0], oy[1], oy[2], oy[3]);
    } else {
        // normalization cancels in the ratio: angle = atan(-yr/xr)
        float a[4];
        double s = 0.0, q = 0.0;
#pragma unroll
        for (int k = 0; k < 4; ++k) {
            float ang = atanf(-yr[k] / xr[k]);
            a[k] = (180.f * ang) / 3.14159274f;
            s += (double)a[k];
            q += (double)a[k] * (double)a[k];
        }
        *(float4*)(xout + obase) = make_float4(a[0], a[1], a[2], a[3]);

        __shared__ double rs[256], rq2[256];
        rs[tid] = s;
        rq2[tid] = q;
        __syncthreads();
        for (int st = 128; st > 0; st >>= 1) {
            if (tid < st) {
                rs[tid] += rs[tid + st];
                rq2[tid] += rq2[tid + st];
            }
            __syncthreads();
        }
        if (tid == 0) {
            int blk = blockIdx.y * 4 + blockIdx.x;  // 256 blocks per channel
            partials[((size_t)ch * 256 + blk) * 2 + 0] = rs[0];
            partials[((size_t)ch * 256 + blk) * 2 + 1] = rq2[0];
        }
    }
}

// ---------------- K5: reduce partials -> mean, invstd per channel ----------------
__global__ __launch_bounds__(256) void k_stats(const double* __restrict__ partials,
                                               float* __restrict__ stats) {
    int ch = blockIdx.x;
    int t = threadIdx.x;
    double s = partials[((size_t)ch * 256 + t) * 2 + 0];
    double q = partials[((size_t)ch * 256 + t) * 2 + 1];
    __shared__ double rs[256], rq[256];
    rs[t] = s;
    rq[t] = q;
    __syncthreads();
    for (int st = 128; st > 0; st >>= 1) {
        if (t < st) {
            rs[t] += rs[t + st];
            rq[t] += rq[t + st];
        }
        __syncthreads();
    }
    if (t == 0) {
        double mean = rs[0] / (double)HW;
        double var = rq[0] / (double)HW - mean * mean;
        stats[ch] = (float)mean;
        stats[6 + ch] = (float)(1.0 / sqrt(var + 1e-5));
    }
}

// ---------------- K6: in-place instance norm on d_out ----------------
__global__ __launch_bounds__(256) void k_norm(float* __restrict__ a,
                                              const float* __restrict__ stats) {
    int ch = blockIdx.y;
    float mean = stats[ch], sc = stats[6 + ch];
    float4* a4 = (float4*)(a + (size_t)ch * HW);
    int i = blockIdx.x * 256 + threadIdx.x;
    float4 v = a4[i];
    v.x = (v.x - mean) * sc;
    v.y = (v.y - mean) * sc;
    v.z = (v.z - mean) * sc;
    v.w = (v.w - mean) * sc;
    a4[i] = v;
}

extern "C" void kernel_launch(void* const* d_in, const int* in_sizes, int n_in,
                              void* d_out, int out_size, void* d_ws, size_t ws_size,
                              hipStream_t stream) {
    (void)in_sizes; (void)n_in; (void)out_size; (void)ws_size;
    const float* img = (const float*)d_in[0];
    float* out = (float*)d_out;

    float* wsf = (float*)d_ws;
    unsigned int* maxbits = (unsigned int*)d_ws;    // [0..5] img max bits, [6..11] gmag max bits
    float* stats = wsf + 16;                        // mean[6], invstd[6]
    double* partials = (double*)(wsf + 32);         // 6*256*2 doubles = 24 KiB
    float* g = wsf + 32768;                         // fields of 6 MiB each
    float* xnA = g + (size_t)NCH * HW;
    float* ynA = xnA + (size_t)NCH * HW;
    float* xnB = ynA + (size_t)NCH * HW;
    float* ynB = xnB + (size_t)NCH * HW;

    dim3 sobel_grid(16, 64, NCH), sobel_blk(32, 8);
    dim3 iter_grid(4, 64, NCH), iter_blk(32, 8);

    k_init<<<dim3(1), dim3(16), 0, stream>>>(maxbits);
    k_imgmax<<<dim3(64, NCH), dim3(256), 0, stream>>>(img, maxbits);
    k_sobel<<<sobel_grid, sobel_blk, 0, stream>>>(img, maxbits, maxbits + 6, g, xnA, ynA);
    k_iter<false><<<iter_grid, iter_blk, 0, stream>>>(g, xnA, ynA, maxbits + 6, xnB, ynB, nullptr);
    k_iter<false><<<iter_grid, iter_blk, 0, stream>>>(g, xnB, ynB, maxbits + 6, xnA, ynA, nullptr);
    k_iter<true><<<iter_grid, iter_blk, 0, stream>>>(g, xnA, ynA, maxbits + 6, out, nullptr, partials);
    k_stats<<<dim3(NCH), dim3(256), 0, stream>>>(partials, stats);
    k_norm<<<dim3(256, NCH), dim3(256), 0, stream>>>(out, stats);
}

// Round 3
// 135.689 us; speedup vs baseline: 1.6144x; 1.4972x over previous
//
#include <hip/hip_runtime.h>
#include <math.h>

#define H 512
#define W 512
#define HW (H * W)
#define NCH 6

__device__ __forceinline__ int reflect_idx(int p, int n) {
    if (p < 0) p = -p;
    if (p >= n) p = 2 * n - 2 - p;
    return p;
}

// ---------------- K1: per-channel partial max of img (no atomics) ----------------
__global__ __launch_bounds__(256) void k_imgmax(const float* __restrict__ img,
                                                float* __restrict__ imgpart) {
    int ch = blockIdx.y;
    int t = threadIdx.x;
    const float4* p4 = (const float4*)(img + (size_t)ch * HW + (size_t)blockIdx.x * 4096);
    float m = 0.f;
#pragma unroll
    for (int k = 0; k < 4; ++k) {
        float4 v = p4[k * 256 + t];
        m = fmaxf(m, fmaxf(fmaxf(v.x, v.y), fmaxf(v.z, v.w)));
    }
    __shared__ float red[256];
    red[t] = m;
    __syncthreads();
    for (int s = 128; s > 0; s >>= 1) {
        if (t < s) red[t] = fmaxf(red[t], red[t + s]);
        __syncthreads();
    }
    if (t == 0) imgpart[ch * 64 + blockIdx.x] = red[0];
}

// ---------------- K1b: reduce 64 partials -> cmax[ch] ----------------
__global__ __launch_bounds__(64) void k_red64(const float* __restrict__ imgpart,
                                              float* __restrict__ cmax) {
    int ch = blockIdx.x;
    float m = imgpart[ch * 64 + threadIdx.x];
#pragma unroll
    for (int k = 32; k > 0; k >>= 1) m = fmaxf(m, __shfl_xor(m, k, 64));
    if (threadIdx.x == 0) cmax[ch] = m;
}

// ---------------- K2: Sobel (LDS-tiled) -> g, xn, yn (rotated), per-block gmag max ----
// Scale-invariance: Sobel on RAW img, then one multiply by 1/cmax before the 1e-12 clamp.
__global__ __launch_bounds__(256) void k_sobel(const float* __restrict__ img,
                                               const float* __restrict__ cmax,
                                               float* __restrict__ gpart,
                                               float* __restrict__ g,
                                               float* __restrict__ xn,
                                               float* __restrict__ yn) {
    const int SW = 36, SH = 10;  // 32x8 tile + halo 1, padded row
    __shared__ float st[SH * SW];

    int ch = blockIdx.z;
    int bx0 = blockIdx.x * 32, by0 = blockIdx.y * 8;
    int tx = threadIdx.x, ty = threadIdx.y;
    int tid = ty * 32 + tx;
    const float* im = img + (size_t)ch * HW;

#pragma unroll
    for (int it = 0; it < 2; ++it) {
        int i = tid + it * 256;
        if (i < SH * 34) {
            int r = i / 34, c = i - r * 34;
            int yy = by0 - 1 + r, xx = bx0 - 1 + c;
            float v = 0.f;
            if (yy >= 0 && yy < H && xx >= 0 && xx < W) v = im[yy * W + xx];  // zero pad
            st[r * SW + c] = v;
        }
    }
    __syncthreads();

    float invc = 1.f / cmax[ch];

    int r = ty + 1, c = tx + 1;
    float a00 = st[(r - 1) * SW + c - 1], a01 = st[(r - 1) * SW + c], a02 = st[(r - 1) * SW + c + 1];
    float a10 = st[r * SW + c - 1], a12 = st[r * SW + c + 1];
    float a20 = st[(r + 1) * SW + c - 1], a21 = st[(r + 1) * SW + c], a22 = st[(r + 1) * SW + c + 1];

    float gx = -a00; gx += a02; gx -= 2.f * a10; gx += 2.f * a12; gx -= a20; gx += a22;
    float gy = -a00; gy -= 2.f * a01; gy -= a02; gy += a20; gy += 2.f * a21; gy += a22;

    gx = fmaxf(gx * invc, 1e-12f);
    gy = fmaxf(gy * invc, 1e-12f);
    float d = gx * gx + gy * gy;
    float rq = __builtin_amdgcn_rsqf(d);
    float gm = d * rq;                 // = sqrt(d), ~1e-7 rel err
    float xv = gx * rq, yv = gy * rq;

    // rotate by fp32(pi/2): ct = cosf, st = 1.0 exactly
    const float ct = -4.37113883e-08f;
    float xr = xv * ct - yv;
    float yr = yv * ct + xv;

    size_t idx = (size_t)ch * HW + (size_t)(by0 + ty) * W + (bx0 + tx);
    g[idx] = gm;
    xn[idx] = xr;
    yn[idx] = yr;

    __syncthreads();  // reuse st for the max reduction
    st[tid] = gm;
    __syncthreads();
    for (int s = 128; s > 0; s >>= 1) {
        if (tid < s) st[tid] = fmaxf(st[tid], st[tid + s]);
        __syncthreads();
    }
    if (tid == 0) gpart[ch * 1024 + blockIdx.y * 16 + blockIdx.x] = st[0];
}

// ---------------- K2b: reduce 1024 partials -> gmax[ch] ----------------
__global__ __launch_bounds__(256) void k_red1024(const float* __restrict__ gpart,
                                                 float* __restrict__ gmax) {
    int ch = blockIdx.x;
    int t = threadIdx.x;
    const float4* p4 = (const float4*)(gpart + ch * 1024);
    float4 v = p4[t];
    float m = fmaxf(fmaxf(v.x, v.y), fmaxf(v.z, v.w));
    __shared__ float red[256];
    red[t] = m;
    __syncthreads();
    for (int s = 128; s > 0; s >>= 1) {
        if (t < s) red[t] = fmaxf(red[t], red[t + s]);
        __syncthreads();
    }
    if (t == 0) gmax[ch] = red[0];
}

// ---------------- K3: one ETF iteration, 4 px/thread (LAST fuses angle+partials) -------
template <bool LAST>
__global__ __launch_bounds__(256) void k_iter(const float* __restrict__ g,
                                              const float* __restrict__ xin,
                                              const float* __restrict__ yin,
                                              const float* __restrict__ gmax,
                                              float* __restrict__ xout,
                                              float* __restrict__ yout,
                                              double* __restrict__ partials) {
    const int SW = 136, SH = 12;  // tile 128x8 + halo 2; row padded to 136 (16B-aligned quads)
    __shared__ __align__(16) float sg[SH * SW];
    __shared__ __align__(16) float sx[SH * SW];
    __shared__ __align__(16) float sy[SH * SW];

    int ch = blockIdx.z;
    int bx0 = blockIdx.x * 128, by0 = blockIdx.y * 8;
    int tx = threadIdx.x, ty = threadIdx.y;
    int tid = ty * 32 + tx;
    const size_t cbase = (size_t)ch * HW;

    // stage rows r: image y = by0-2+r ; cols c (0..131): image x = bx0-2+c (reflect)
    for (int i = tid; i < SH * 132; i += 256) {
        int r = i / 132, c = i - r * 132;
        int yy = reflect_idx(by0 - 2 + r, H);
        int xx = reflect_idx(bx0 - 2 + c, W);
        size_t idx = cbase + (size_t)yy * W + xx;
        int s = r * SW + c;
        sg[s] = g[idx];
        sx[s] = xin[idx];
        sy[s] = yin[idx];
    }
    __syncthreads();

    float inv = 1.f / gmax[ch];
    float s2 = -2.f * inv;  // sigmoid(2*inv*d) = 0.5*(1+tanh(inv*d))

    // thread handles pixels x = bx0 + 4*tx + k, k=0..3; LDS center col = 4*tx+2+k
    auto ld8 = [&](const float* s, int r, float* w) {
        const float4* p = (const float4*)(s + r * SW + 4 * tx);
        float4 a = p[0], b = p[1];
        w[0] = a.x; w[1] = a.y; w[2] = a.z; w[3] = a.w;
        w[4] = b.x; w[5] = b.y; w[6] = b.z; w[7] = b.w;
    };

    int row0 = ty + 2;
    float cgw[8], cxw[8], cyw[8];
    ld8(sg, row0, cgw);
    ld8(sx, row0, cxw);
    ld8(sy, row0, cyw);
    float cg[4], cx[4], cy[4], ec[4];
#pragma unroll
    for (int k = 0; k < 4; ++k) {
        cg[k] = cgw[k + 2];
        cx[k] = cxw[k + 2];
        cy[k] = cyw[k + 2];
        ec[k] = __expf(-s2 * cg[k]);  // e^{s2(ng-cg)} = e^{s2 ng} * ec
    }

    float xr[4] = {0.f, 0.f, 0.f, 0.f}, yr[4] = {0.f, 0.f, 0.f, 0.f};
#pragma unroll
    for (int dy = -2; dy <= 2; ++dy) {
        float gw[8], xw[8], yw[8], ew[8];
        ld8(sg, row0 + dy, gw);
        ld8(sx, row0 + dy, xw);
        ld8(sy, row0 + dy, yw);
#pragma unroll
        for (int n = 0; n < 8; ++n) ew[n] = __expf(s2 * gw[n]);
#pragma unroll
        for (int k = 0; k < 4; ++k) {
#pragma unroll
            for (int dxi = 0; dxi < 5; ++dxi) {
                int n = k + dxi;
                float dot = cx[k] * xw[n] + cy[k] * yw[n];
                float wm = __builtin_amdgcn_rcpf(1.f + ew[n] * ec[k]);
                float m = gw[n] * (wm * dot);
                xr[k] = fmaf(m, xw[n], xr[k]);
                yr[k] = fmaf(m, yw[n], yr[k]);
            }
        }
    }

    size_t obase = cbase + (size_t)(by0 + ty) * W + bx0 + 4 * tx;
    if (!LAST) {
        float ox[4], oy[4];
#pragma unroll
        for (int k = 0; k < 4; ++k) {
            float im2 = __builtin_amdgcn_rsqf(xr[k] * xr[k] + yr[k] * yr[k]);
            ox[k] = xr[k] * im2;
            oy[k] = yr[k] * im2;
        }
        *(float4*)(xout + obase) = make_float4(ox[0], ox[1], ox[2], ox[3]);
        *(float4*)(yout + obase) = make_float4(oy[0], oy[1], oy[2], oy[3]);
    } else {
        // normalization cancels in the ratio: angle = atan(-yr/xr)
        float a[4];
        double s = 0.0, q = 0.0;
#pragma unroll
        for (int k = 0; k < 4; ++k) {
            float ang = atanf(-yr[k] / xr[k]);
            a[k] = (180.f * ang) / 3.14159274f;
            s += (double)a[k];
            q += (double)a[k] * (double)a[k];
        }
        *(float4*)(xout + obase) = make_float4(a[0], a[1], a[2], a[3]);

        __shared__ double rs[256], rq2[256];
        rs[tid] = s;
        rq2[tid] = q;
        __syncthreads();
        for (int st = 128; st > 0; st >>= 1) {
            if (tid < st) {
                rs[tid] += rs[tid + st];
                rq2[tid] += rq2[tid + st];
            }
            __syncthreads();
        }
        if (tid == 0) {
            int blk = blockIdx.y * 4 + blockIdx.x;  // 256 blocks per channel
            partials[((size_t)ch * 256 + blk) * 2 + 0] = rs[0];
            partials[((size_t)ch * 256 + blk) * 2 + 1] = rq2[0];
        }
    }
}

// ---------------- K5: reduce partials -> mean, invstd per channel ----------------
__global__ __launch_bounds__(256) void k_stats(const double* __restrict__ partials,
                                               float* __restrict__ stats) {
    int ch = blockIdx.x;
    int t = threadIdx.x;
    double s = partials[((size_t)ch * 256 + t) * 2 + 0];
    double q = partials[((size_t)ch * 256 + t) * 2 + 1];
    __shared__ double rs[256], rq[256];
    rs[t] = s;
    rq[t] = q;
    __syncthreads();
    for (int st = 128; st > 0; st >>= 1) {
        if (t < st) {
            rs[t] += rs[t + st];
            rq[t] += rq[t + st];
        }
        __syncthreads();
    }
    if (t == 0) {
        double mean = rs[0] / (double)HW;
        double var = rq[0] / (double)HW - mean * mean;
        stats[ch] = (float)mean;
        stats[6 + ch] = (float)(1.0 / sqrt(var + 1e-5));
    }
}

// ---------------- K6: in-place instance norm on d_out ----------------
__global__ __launch_bounds__(256) void k_norm(float* __restrict__ a,
                                              const float* __restrict__ stats) {
    int ch = blockIdx.y;
    float mean = stats[ch], sc = stats[6 + ch];
    float4* a4 = (float4*)(a + (size_t)ch * HW);
    int i = blockIdx.x * 256 + threadIdx.x;
    float4 v = a4[i];
    v.x = (v.x - mean) * sc;
    v.y = (v.y - mean) * sc;
    v.z = (v.z - mean) * sc;
    v.w = (v.w - mean) * sc;
    a4[i] = v;
}

extern "C" void kernel_launch(void* const* d_in, const int* in_sizes, int n_in,
                              void* d_out, int out_size, void* d_ws, size_t ws_size,
                              hipStream_t stream) {
    (void)in_sizes; (void)n_in; (void)out_size; (void)ws_size;
    const float* img = (const float*)d_in[0];
    float* out = (float*)d_out;

    float* wsf = (float*)d_ws;
    float* cmax = wsf + 0;                          // [6]
    float* gmax = wsf + 8;                          // [6]
    float* stats = wsf + 16;                        // mean[6], invstd[6]
    float* imgpart = wsf + 64;                      // 6*64
    float* gpart = wsf + 512;                       // 6*1024
    double* partials = (double*)(wsf + 8192);       // 6*256*2 doubles = 24 KiB
    float* g = wsf + 32768;                         // fields of 6 MiB each
    float* xnA = g + (size_t)NCH * HW;
    float* ynA = xnA + (size_t)NCH * HW;
    float* xnB = ynA + (size_t)NCH * HW;
    float* ynB = xnB + (size_t)NCH * HW;

    dim3 sobel_grid(16, 64, NCH), sobel_blk(32, 8);
    dim3 iter_grid(4, 64, NCH), iter_blk(32, 8);

    k_imgmax<<<dim3(64, NCH), dim3(256), 0, stream>>>(img, imgpart);
    k_red64<<<dim3(NCH), dim3(64), 0, stream>>>(imgpart, cmax);
    k_sobel<<<sobel_grid, sobel_blk, 0, stream>>>(img, cmax, gpart, g, xnA, ynA);
    k_red1024<<<dim3(NCH), dim3(256), 0, stream>>>(gpart, gmax);
    k_iter<false><<<iter_grid, iter_blk, 0, stream>>>(g, xnA, ynA, gmax, xnB, ynB, nullptr);
    k_iter<false><<<iter_grid, iter_blk, 0, stream>>>(g, xnB, ynB, gmax, xnA, ynA, nullptr);
    k_iter<true><<<iter_grid, iter_blk, 0, stream>>>(g, xnA, ynA, gmax, out, nullptr, partials);
    k_stats<<<dim3(NCH), dim3(256), 0, stream>>>(partials, stats);
    k_norm<<<dim3(256, NCH), dim3(256), 0, stream>>>(out, stats);
}

// Round 4
// 132.355 us; speedup vs baseline: 1.6551x; 1.0252x over previous
//
#include <hip/hip_runtime.h>
#include <math.h>

#define H 512
#define W 512
#define HW (H * W)
#define NCH 6

__device__ __forceinline__ int reflect_idx(int p, int n) {
    if (p < 0) p = -p;
    if (p >= n) p = 2 * n - 2 - p;
    return p;
}

// ---------------- K1: Sobel (LDS-tiled, 128x8, 4 px/thread interleaved) ----------------
// cmax (per-channel img max) is dropped: the pipeline is scale-invariant past the clamp
// (xn = gx/gm, gnorm = gm/gmax, output = atan of a ratio); cmax only rescales the 1e-12
// clamp threshold by ~0.99999 -> effect ~1e-6 of threshold. Sobel runs on RAW img.
__global__ __launch_bounds__(256) void k_sobel(const float* __restrict__ img,
                                               float* __restrict__ gpart,
                                               float* __restrict__ g,
                                               float* __restrict__ xn,
                                               float* __restrict__ yn) {
    const int SW = 132, SH = 10;  // 128x8 tile + halo 1 (130 cols used), stride 132
    __shared__ float st[SH * SW];

    int ch = blockIdx.z;
    int bx0 = blockIdx.x * 128, by0 = blockIdx.y * 8;
    int tx = threadIdx.x, ty = threadIdx.y;
    int tid = ty * 32 + tx;
    const float* im = img + (size_t)ch * HW;

    for (int i = tid; i < SH * 130; i += 256) {
        int r = i / 130, c = i - r * 130;
        int yy = by0 - 1 + r, xx = bx0 - 1 + c;
        float v = 0.f;
        if (yy >= 0 && yy < H && xx >= 0 && xx < W) v = im[yy * W + xx];  // zero pad
        st[r * SW + c] = v;
    }
    __syncthreads();

    float bmax = 0.f;
    int y = by0 + ty;
    int r = ty + 1;
    float gm4[4], xr4[4], yr4[4];
#pragma unroll
    for (int k = 0; k < 4; ++k) {
        int c = tx + 32 * k + 1;  // LDS col of the pixel
        float a00 = st[(r - 1) * SW + c - 1], a01 = st[(r - 1) * SW + c], a02 = st[(r - 1) * SW + c + 1];
        float a10 = st[r * SW + c - 1], a12 = st[r * SW + c + 1];
        float a20 = st[(r + 1) * SW + c - 1], a21 = st[(r + 1) * SW + c], a22 = st[(r + 1) * SW + c + 1];

        float gx = (a02 - a00) + 2.f * (a12 - a10) + (a22 - a20);
        float gy = (a20 - a00) + 2.f * (a21 - a01) + (a22 - a02);

        gx = fmaxf(gx, 1e-12f);
        gy = fmaxf(gy, 1e-12f);
        float d = gx * gx + gy * gy;
        float rq = __builtin_amdgcn_rsqf(d);
        float gm = d * rq;  // sqrt(d)
        float xv = gx * rq, yv = gy * rq;
        // rotate by fp32(pi/2): ct = cosf(1.5707964f), st = 1.0 exactly
        const float ct = -4.37113883e-08f;
        gm4[k] = gm;
        xr4[k] = xv * ct - yv;
        yr4[k] = yv * ct + xv;
        bmax = fmaxf(bmax, gm);
    }
#pragma unroll
    for (int k = 0; k < 4; ++k) {
        int idx = y * W + bx0 + tx + 32 * k;
        float* gc = g + (size_t)ch * HW;
        float* xc = xn + (size_t)ch * HW;
        float* yc = yn + (size_t)ch * HW;
        gc[idx] = gm4[k];
        xc[idx] = xr4[k];
        yc[idx] = yr4[k];
    }

    __syncthreads();  // reuse st for the max reduction
    st[tid] = bmax;
    __syncthreads();
    for (int s = 128; s > 0; s >>= 1) {
        if (tid < s) st[tid] = fmaxf(st[tid], st[tid + s]);
        __syncthreads();
    }
    if (tid == 0) gpart[ch * 256 + blockIdx.y * 4 + blockIdx.x] = st[0];
}

// ---------------- K2: one ETF iteration, 4 px/thread (LAST fuses angle+partials) -------
// gmax is reduced inline from gpart by wave 0 during staging (no extra kernel).
template <bool LAST>
__global__ __launch_bounds__(256) void k_iter(const float* __restrict__ g,
                                              const float* __restrict__ xin,
                                              const float* __restrict__ yin,
                                              const float* __restrict__ gpart,
                                              float* __restrict__ xout,
                                              float* __restrict__ yout,
                                              double* __restrict__ partials) {
    const int SW = 136, SH = 12;  // tile 128x8 + halo 2; 132 cols used, stride 136
    __shared__ __align__(16) float sg[SH * SW];
    __shared__ __align__(16) float se[SH * SW];
    __shared__ __align__(16) float sx[SH * SW];
    __shared__ __align__(16) float sy[SH * SW];
    __shared__ float smax;

    int ch = blockIdx.z;
    int bx0 = blockIdx.x * 128, by0 = blockIdx.y * 8;
    int tx = threadIdx.x, ty = threadIdx.y;
    int tid = ty * 32 + tx;

    // wave 0: reduce this channel's 256 sobel-block maxima -> smax
    if (tid < 64) {
        const float* gp = gpart + ch * 256;
        float m = fmaxf(fmaxf(gp[tid], gp[tid + 64]), fmaxf(gp[tid + 128], gp[tid + 192]));
#pragma unroll
        for (int k = 32; k > 0; k >>= 1) m = fmaxf(m, __shfl_xor(m, k, 64));
        if (tid == 0) smax = m;
    }

    // stage g/x/y (keep g values in regs for the exp phase)
    const float* gc = g + (size_t)ch * HW;
    const float* xc = xin + (size_t)ch * HW;
    const float* yc = yin + (size_t)ch * HW;
    float vg[7];
    int nj = 0;
    for (int i = tid; i < SH * 132; i += 256, ++nj) {
        int r = i / 132, c = i - r * 132;
        int yy = reflect_idx(by0 - 2 + r, H);
        int xx = reflect_idx(bx0 - 2 + c, W);
        int idx = yy * W + xx;
        int s = r * SW + c;
        float gv = gc[idx];
        vg[nj] = gv;
        sg[s] = gv;
        sx[s] = xc[idx];
        sy[s] = yc[idx];
    }
    __syncthreads();

    float inv = __builtin_amdgcn_rcpf(smax);
    float s2 = -2.f * inv;  // sigmoid(2*inv*d) = 0.5*(1+tanh(inv*d))

    // phase 2: se = exp(s2*g) once per staged pixel (reuses reg-held g)
    nj = 0;
    for (int i = tid; i < SH * 132; i += 256, ++nj) {
        int r = i / 132, c = i - r * 132;
        se[r * SW + c] = __expf(s2 * vg[nj]);
    }
    __syncthreads();

    auto ld8 = [&](const float* s, int r, float* w) {
        const float4* p = (const float4*)(s + r * SW + 4 * tx);
        float4 a = p[0], b = p[1];
        w[0] = a.x; w[1] = a.y; w[2] = a.z; w[3] = a.w;
        w[4] = b.x; w[5] = b.y; w[6] = b.z; w[7] = b.w;
    };

    int row0 = ty + 2;
    float cxw[8], cyw[8], cew[8];
    ld8(sx, row0, cxw);
    ld8(sy, row0, cyw);
    ld8(se, row0, cew);
    float cx[4], cy[4], ec[4];
#pragma unroll
    for (int k = 0; k < 4; ++k) {
        cx[k] = cxw[k + 2];
        cy[k] = cyw[k + 2];
        ec[k] = __builtin_amdgcn_rcpf(cew[k + 2]);  // e^{+2 cg/gmax}
    }

    float xr[4] = {0.f, 0.f, 0.f, 0.f}, yr[4] = {0.f, 0.f, 0.f, 0.f};
#pragma unroll
    for (int dy = -2; dy <= 2; ++dy) {
        float gw[8], xw[8], yw[8], ew[8];
        ld8(sg, row0 + dy, gw);
        ld8(sx, row0 + dy, xw);
        ld8(sy, row0 + dy, yw);
        ld8(se, row0 + dy, ew);
#pragma unroll
        for (int k = 0; k < 4; ++k) {
#pragma unroll
            for (int dxi = 0; dxi < 5; ++dxi) {
                int n = k + dxi;
                float dot = cx[k] * xw[n] + cy[k] * yw[n];
                float wm = __builtin_amdgcn_rcpf(1.f + ew[n] * ec[k]);
                float m = gw[n] * (wm * dot);
                xr[k] = fmaf(m, xw[n], xr[k]);
                yr[k] = fmaf(m, yw[n], yr[k]);
            }
        }
    }

    int obase = (by0 + ty) * W + bx0 + 4 * tx;
    if (!LAST) {
        float* xo = xout + (size_t)ch * HW;
        float* yo = yout + (size_t)ch * HW;
        float ox[4], oy[4];
#pragma unroll
        for (int k = 0; k < 4; ++k) {
            float im2 = __builtin_amdgcn_rsqf(xr[k] * xr[k] + yr[k] * yr[k]);
            ox[k] = xr[k] * im2;
            oy[k] = yr[k] * im2;
        }
        *(float4*)(xo + obase) = make_float4(ox[0], ox[1], ox[2], ox[3]);
        *(float4*)(yo + obase) = make_float4(oy[0], oy[1], oy[2], oy[3]);
    } else {
        // normalization cancels in the ratio: angle = atan(-yr/xr)
        float a[4];
        double s = 0.0, q = 0.0;
#pragma unroll
        for (int k = 0; k < 4; ++k) {
            float ang = atanf(-yr[k] / xr[k]);
            a[k] = (180.f * ang) / 3.14159274f;
            s += (double)a[k];
            q += (double)a[k] * (double)a[k];
        }
        float* xo = xout + (size_t)ch * HW;
        *(float4*)(xo + obase) = make_float4(a[0], a[1], a[2], a[3]);

        __shared__ double rs[256], rq2[256];
        rs[tid] = s;
        rq2[tid] = q;
        __syncthreads();
        for (int st = 128; st > 0; st >>= 1) {
            if (tid < st) {
                rs[tid] += rs[tid + st];
                rq2[tid] += rq2[tid + st];
            }
            __syncthreads();
        }
        if (tid == 0) {
            int blk = blockIdx.y * 4 + blockIdx.x;  // 256 blocks per channel
            partials[((size_t)ch * 256 + blk) * 2 + 0] = rs[0];
            partials[((size_t)ch * 256 + blk) * 2 + 1] = rq2[0];
        }
    }
}

// ---------------- K3: instance norm (inline stats reduce, then normalize) ----------------
__global__ __launch_bounds__(256) void k_norm(float* __restrict__ a,
                                              const double* __restrict__ partials) {
    int ch = blockIdx.y;
    int t = threadIdx.x;

    __shared__ double rs[256], rq[256];
    rs[t] = partials[((size_t)ch * 256 + t) * 2 + 0];
    rq[t] = partials[((size_t)ch * 256 + t) * 2 + 1];
    __syncthreads();
    for (int st = 128; st > 0; st >>= 1) {
        if (t < st) {
            rs[t] += rs[t + st];
            rq[t] += rq[t + st];
        }
        __syncthreads();
    }
    __shared__ float sm, ss;
    if (t == 0) {
        double mean = rs[0] / (double)HW;
        double var = rq[0] / (double)HW - mean * mean;
        sm = (float)mean;
        ss = (float)(1.0 / sqrt(var + 1e-5));
    }
    __syncthreads();
    float mean = sm, sc = ss;

    float4* a4 = (float4*)(a + (size_t)ch * HW + (size_t)blockIdx.x * 4096);
#pragma unroll
    for (int k = 0; k < 4; ++k) {
        float4 v = a4[k * 256 + t];
        v.x = (v.x - mean) * sc;
        v.y = (v.y - mean) * sc;
        v.z = (v.z - mean) * sc;
        v.w = (v.w - mean) * sc;
        a4[k * 256 + t] = v;
    }
}

extern "C" void kernel_launch(void* const* d_in, const int* in_sizes, int n_in,
                              void* d_out, int out_size, void* d_ws, size_t ws_size,
                              hipStream_t stream) {
    (void)in_sizes; (void)n_in; (void)out_size; (void)ws_size;
    const float* img = (const float*)d_in[0];
    float* out = (float*)d_out;

    float* wsf = (float*)d_ws;
    float* gpart = wsf + 512;                       // 6*256
    double* partials = (double*)(wsf + 8192);       // 6*256*2 doubles = 24 KiB
    float* g = wsf + 32768;                         // fields of 6 MiB each (1 MiB/ch * 6)
    float* xnA = g + (size_t)NCH * HW;
    float* ynA = xnA + (size_t)NCH * HW;
    float* xnB = ynA + (size_t)NCH * HW;
    float* ynB = xnB + (size_t)NCH * HW;

    dim3 tile_grid(4, 64, NCH), tile_blk(32, 8);

    k_sobel<<<tile_grid, tile_blk, 0, stream>>>(img, gpart, g, xnA, ynA);
    k_iter<false><<<tile_grid, tile_blk, 0, stream>>>(g, xnA, ynA, gpart, xnB, ynB, nullptr);
    k_iter<false><<<tile_grid, tile_blk, 0, stream>>>(g, xnB, ynB, gpart, xnA, ynA, nullptr);
    k_iter<true><<<tile_grid, tile_blk, 0, stream>>>(g, xnA, ynA, gpart, out, nullptr, partials);
    k_norm<<<dim3(64, NCH), dim3(256), 0, stream>>>(out, partials);
}